// Round 14
// baseline (446.436 us; speedup 1.0000x reference)
//
#include <hip/hip_runtime.h>
#include <stdint.h>

#define D 768
#define FCH 16     // filter chunks per query
#define CPC 16     // candidates kept per chunk
#define NCAND 256  // FCH * CPC

typedef __bf16 bf16x8 __attribute__((ext_vector_type(8)));
typedef float  f32x4  __attribute__((ext_vector_type(4)));
typedef float  f32x2  __attribute__((ext_vector_type(2)));

static __device__ __forceinline__ float b2f(unsigned short u){
    union { unsigned int i; float f; } v; v.i = ((unsigned int)u) << 16; return v.f;
}
static __device__ __forceinline__ unsigned short f2b(float f){
    union { float f; unsigned int i; } v; v.f = f;
    unsigned int u = v.i;
    unsigned int r = (u + 0x7fffu + ((u >> 16) & 1u)) >> 16;
    return (unsigned short)r;
}
static __device__ __forceinline__ void gload_lds16(const void* g, void* l){
    __builtin_amdgcn_global_load_lds((const __attribute__((address_space(1))) void*)g,
                                     (__attribute__((address_space(3))) void*)l, 16, 0, 0);
}
static __device__ __forceinline__ void dec4_fma(unsigned int u, float nm, float* acc){
    f32x2 a = __builtin_amdgcn_cvt_pk_f32_fp8((int)u, false);
    f32x2 b = __builtin_amdgcn_cvt_pk_f32_fp8((int)u, true);
    acc[0] += a[0] * nm; acc[1] += a[1] * nm;
    acc[2] += b[0] * nm; acc[3] += b[1] * nm;
}
static __device__ __forceinline__ unsigned char f2fp8(float f){
    int p = __builtin_amdgcn_cvt_pk_fp8_f32(f, 0.0f, 0, false);
    return (unsigned char)(p & 0xFF);
}
static __device__ __forceinline__ unsigned int pk4_fp8(float a, float b, float c, float d){
    int lo = __builtin_amdgcn_cvt_pk_fp8_f32(a, b, 0, false);
    int fu = __builtin_amdgcn_cvt_pk_fp8_f32(c, d, lo, true);
    return (unsigned int)fu;
}

// ---------------- fused f32 -> fp8 conversion for x and q ----------------
__global__ __launch_bounds__(256) void cvt8_fused(const float* __restrict__ x,
                                                  unsigned char* __restrict__ y8, size_t nxq,
                                                  const float* __restrict__ qq,
                                                  unsigned char* __restrict__ q8, size_t nqq){
    size_t i = (size_t)blockIdx.x * 256 + threadIdx.x;   // quad index
    if (i < nxq){
        f32x4 v = *(const f32x4*)(x + i * 4);
        *(unsigned int*)(y8 + i * 4) = pk4_fp8(v[0], v[1], v[2], v[3]);
    } else if (i - nxq < nqq){
        size_t j = i - nxq;
        f32x4 v = *(const f32x4*)(qq + j * 4);
        *(unsigned int*)(q8 + j * 4) = pk4_fp8(v[0], v[1], v[2], v[3]);
    }
}

// ---------------- W [D][D] f32 -> Wt [n][k] fp8 (both weights, z-indexed) ----------------
__global__ __launch_bounds__(256) void transposeW8(const float* __restrict__ W1,
                                                   unsigned char* __restrict__ W1t,
                                                   const float* __restrict__ W2,
                                                   unsigned char* __restrict__ W2t){
    const float* W = blockIdx.z ? W2 : W1;
    unsigned char* Wt = blockIdx.z ? W2t : W1t;
    __shared__ unsigned char tile[32][33];
    int bx = blockIdx.x * 32;   // k base
    int by = blockIdx.y * 32;   // n base
    int tx = threadIdx.x & 31, ty = threadIdx.x >> 5;
    #pragma unroll
    for (int r = 0; r < 32; r += 8)
        tile[ty + r][tx] = f2fp8(W[(size_t)(bx + ty + r) * D + by + tx]);
    __syncthreads();
    #pragma unroll
    for (int r = 0; r < 32; r += 8)
        Wt[(size_t)(by + ty + r) * D + bx + tx] = tile[tx][ty + r];
}

// ---------------- prep: zero cnt, flag, rcp in one dispatch ----------------
__global__ __launch_bounds__(256) void prep_zero(int* __restrict__ cnt, int* __restrict__ flag,
                                                 int* __restrict__ rcp, int N){
    int i = blockIdx.x * 256 + threadIdx.x;
    if (i < N){ cnt[i] = 0; flag[i] = 0; }
    if (i == 0) rcp[0] = 0;
}

// ---------------- degree / dis / CSR ----------------
__global__ __launch_bounds__(256) void deg_count(const int* __restrict__ dst, int* cnt, int E){
    int e = blockIdx.x * 256 + threadIdx.x;
    if (e < E) atomicAdd(&cnt[dst[e]], 1);
}
__global__ __launch_bounds__(256) void dis_blocksum(const int* __restrict__ cnt,
                                                    float* __restrict__ dis,
                                                    int* __restrict__ bsum, int N){
    __shared__ int sm[256];
    int tid = threadIdx.x;
    int i = blockIdx.x * 256 + tid;
    int c = (i < N) ? cnt[i] : 0;
    if (i < N) dis[i] = rsqrtf((float)(c + 1));
    sm[tid] = c;
    __syncthreads();
    for (int o = 128; o > 0; o >>= 1){
        if (tid < o) sm[tid] += sm[tid + o];
        __syncthreads();
    }
    if (tid == 0) bsum[blockIdx.x] = sm[0];
}
__global__ __launch_bounds__(256) void scanb_k(const int* __restrict__ bsum, int* boff, int nb){
    __shared__ int sm[256];
    int tid = threadIdx.x;
    int v = (tid < nb) ? bsum[tid] : 0;
    sm[tid] = v;
    __syncthreads();
    for (int o = 1; o < 256; o <<= 1){
        int add = (tid >= o) ? sm[tid - o] : 0;
        __syncthreads();
        sm[tid] += add;
        __syncthreads();
    }
    if (tid < nb) boff[tid] = sm[tid] - v;
}
__global__ __launch_bounds__(256) void scanfin_k(const int* __restrict__ cnt,
                                                 const int* __restrict__ boff,
                                                 int* start, int* fill, int N, int E){
    __shared__ int sm[256];
    int tid = threadIdx.x;
    int i = blockIdx.x * 256 + tid;
    int v = (i < N) ? cnt[i] : 0;
    sm[tid] = v;
    __syncthreads();
    for (int o = 1; o < 256; o <<= 1){
        int add = (tid >= o) ? sm[tid - o] : 0;
        __syncthreads();
        sm[tid] += add;
        __syncthreads();
    }
    if (i < N){ start[i] = boff[blockIdx.x] + sm[tid] - v; fill[i] = 0; }
    if (i == 0) start[N] = E;
}
__global__ __launch_bounds__(256) void csr_fill(const int* __restrict__ src,
                                                const int* __restrict__ dst,
                                                const float* __restrict__ dis,
                                                const int* __restrict__ start,
                                                int* fill, int* csr_src, float* csr_norm, int E){
    int e = blockIdx.x * 256 + threadIdx.x;
    if (e >= E) return;
    int s = src[e], d = dst[e];
    int pos = atomicAdd(&fill[d], 1);
    int idx = start[d] + pos;
    csr_src[idx]  = s;
    csr_norm[idx] = dis[s] * dis[d];
}

// ---------------- fp8 MFMA GEMM (full M): C = A8[M][768] @ W8, fp8 out ----------------
// BK=64: 12 K-iters, 2 MFMA sub-steps per barrier pair. LDS 2x8KB linear [128][64] byte rows.
__global__ __launch_bounds__(256) void gemm_fp8(const unsigned char* __restrict__ A,
                                                const unsigned char* __restrict__ Bt,
                                                unsigned char* __restrict__ Cout,
                                                int M, int nTilesN){
    __shared__ unsigned char Al[128 * 64];
    __shared__ unsigned char Bl[128 * 64];
    const int nwg = gridDim.x;
    const int bid = blockIdx.x;
    const int q = nwg >> 3, r = nwg & 7;
    const int xcd = bid & 7, loc = bid >> 3;
    const int swz = (xcd < r ? xcd * (q + 1) : r * (q + 1) + (xcd - r) * q) + loc;
    const int mt = swz / nTilesN, nt = swz % nTilesN;
    const int m0 = mt * 128, n0 = nt * 128;

    const int tid  = threadIdx.x;
    const int lane = tid & 63;
    const int w    = tid >> 6;
    const int wr = w >> 1, wc = w & 1;
    const int l15 = lane & 15;
    const int lg  = lane >> 4;

    // staging: 512 granules of 16B per matrix; thread t handles g=t and g=t+256.
    const int row0 = tid >> 2,        q0 = (tid & 3) * 16;          // g = tid
    const int row1 = (tid + 256) >> 2, q1 = ((tid + 256) & 3) * 16; // g = tid+256

    f32x4 acc[4][4] = {};

    for (int k0 = 0; k0 < D; k0 += 64){
        gload_lds16(A  + (size_t)(m0 + row0) * D + k0 + q0, (char*)Al + tid * 16);
        gload_lds16(A  + (size_t)(m0 + row1) * D + k0 + q1, (char*)Al + (tid + 256) * 16);
        gload_lds16(Bt + (size_t)(n0 + row0) * D + k0 + q0, (char*)Bl + tid * 16);
        gload_lds16(Bt + (size_t)(n0 + row1) * D + k0 + q1, (char*)Bl + (tid + 256) * 16);
        __syncthreads();
        #pragma unroll
        for (int ks = 0; ks < 2; ks++){
            long af[4], bfv[4];
            #pragma unroll
            for (int mf = 0; mf < 4; mf++)
                af[mf] = *(const long*)(&Al[(wr * 64 + mf * 16 + l15) * 64 + ks * 32 + lg * 8]);
            #pragma unroll
            for (int nf = 0; nf < 4; nf++)
                bfv[nf] = *(const long*)(&Bl[(wc * 64 + nf * 16 + l15) * 64 + ks * 32 + lg * 8]);
            #pragma unroll
            for (int mf = 0; mf < 4; mf++)
                #pragma unroll
                for (int nf = 0; nf < 4; nf++)
                    acc[mf][nf] = __builtin_amdgcn_mfma_f32_16x16x32_fp8_fp8(af[mf], bfv[nf], acc[mf][nf], 0, 0, 0);
        }
        __syncthreads();
    }
    #pragma unroll
    for (int mf = 0; mf < 4; mf++){
        #pragma unroll
        for (int r2 = 0; r2 < 4; r2++){
            int gr = m0 + wr * 64 + mf * 16 + lg * 4 + r2;
            if (gr < M){
                #pragma unroll
                for (int nf = 0; nf < 4; nf++){
                    int gc = n0 + wc * 64 + nf * 16 + l15;
                    Cout[(size_t)gr * D + gc] = f2fp8(acc[mf][nf][r2]);
                }
            }
        }
    }
}

// ---------------- row-list fp8 GEMM (BK=64): C[RL[i]] = A8[RL[i]] @ W8 for i < *rcp ----------
__global__ __launch_bounds__(256) void gemm_fp8_list(const unsigned char* __restrict__ A,
                                                     const unsigned char* __restrict__ Bt,
                                                     unsigned char* __restrict__ Cout,
                                                     const int* __restrict__ RL,
                                                     const int* __restrict__ rcp,
                                                     int nTilesN){
    const int rc = *rcp;
    __shared__ unsigned char Al[128 * 64];
    __shared__ unsigned char Bl[128 * 64];
    __shared__ int rlTile[128];
    const int nwg = gridDim.x;
    const int bid = blockIdx.x;
    const int q = nwg >> 3, r = nwg & 7;
    const int xcd = bid & 7, loc = bid >> 3;
    const int swz = (xcd < r ? xcd * (q + 1) : r * (q + 1) + (xcd - r) * q) + loc;
    const int mt = swz / nTilesN, nt = swz % nTilesN;
    const int m0 = mt * 128, n0 = nt * 128;
    if (m0 >= rc) return;

    const int tid  = threadIdx.x;
    if (tid < 128){
        int p = m0 + tid;
        rlTile[tid] = RL[p < rc ? p : rc - 1];
    }
    const int lane = tid & 63;
    const int w    = tid >> 6;
    const int wr = w >> 1, wc = w & 1;
    const int l15 = lane & 15;
    const int lg  = lane >> 4;

    const int row0 = tid >> 2,        q0 = (tid & 3) * 16;
    const int row1 = (tid + 256) >> 2, q1 = ((tid + 256) & 3) * 16;
    __syncthreads();
    const int arow0 = rlTile[row0];
    const int arow1 = rlTile[row1];

    f32x4 acc[4][4] = {};

    for (int k0 = 0; k0 < D; k0 += 64){
        gload_lds16(A  + (size_t)arow0 * D + k0 + q0, (char*)Al + tid * 16);
        gload_lds16(A  + (size_t)arow1 * D + k0 + q1, (char*)Al + (tid + 256) * 16);
        gload_lds16(Bt + (size_t)(n0 + row0) * D + k0 + q0, (char*)Bl + tid * 16);
        gload_lds16(Bt + (size_t)(n0 + row1) * D + k0 + q1, (char*)Bl + (tid + 256) * 16);
        __syncthreads();
        #pragma unroll
        for (int ks = 0; ks < 2; ks++){
            long af[4], bfv[4];
            #pragma unroll
            for (int mf = 0; mf < 4; mf++)
                af[mf] = *(const long*)(&Al[(wr * 64 + mf * 16 + l15) * 64 + ks * 32 + lg * 8]);
            #pragma unroll
            for (int nf = 0; nf < 4; nf++)
                bfv[nf] = *(const long*)(&Bl[(wc * 64 + nf * 16 + l15) * 64 + ks * 32 + lg * 8]);
            #pragma unroll
            for (int mf = 0; mf < 4; mf++)
                #pragma unroll
                for (int nf = 0; nf < 4; nf++)
                    acc[mf][nf] = __builtin_amdgcn_mfma_f32_16x16x32_fp8_fp8(af[mf], bfv[nf], acc[mf][nf], 0, 0, 0);
        }
        __syncthreads();
    }
    #pragma unroll
    for (int mf = 0; mf < 4; mf++){
        #pragma unroll
        for (int r2 = 0; r2 < 4; r2++){
            int lr = wr * 64 + mf * 16 + lg * 4 + r2;
            if (m0 + lr < rc){
                int gr = rlTile[lr];
                #pragma unroll
                for (int nf = 0; nf < 4; nf++){
                    int gc = n0 + wc * 64 + nf * 16 + l15;
                    Cout[(size_t)gr * D + gc] = f2fp8(acc[mf][nf][r2]);
                }
            }
        }
    }
}

// ---------------- GCN aggregation (fp8 gather). LIST: rows from list; Mp: device count ----
template<bool OUT8, bool LIST>
__global__ __launch_bounds__(256) void agg_fp8(const unsigned char* __restrict__ h8,
                                               void* __restrict__ out,
                                               const int* __restrict__ start,
                                               const int* __restrict__ csr_src,
                                               const float* __restrict__ csr_norm,
                                               const float* __restrict__ dis,
                                               const float* __restrict__ bias,
                                               const int* __restrict__ list,
                                               const int* __restrict__ Mp,
                                               int doRelu, int M){
    if (Mp) M = *Mp;
    int pair = blockIdx.x * 4 + (threadIdx.x >> 6);
    if (pair >= M) return;
    int wid = LIST ? list[pair] : pair;
    int lane = threadIdx.x & 63;
    const int lo = lane * 12;
    float acc[12] = {};
    float dn = dis[wid];
    float sn = dn * dn;
    {
        const unsigned char* hr = h8 + (size_t)wid * D + lo;
        unsigned int u0 = *(const unsigned int*)(hr);
        unsigned int u1 = *(const unsigned int*)(hr + 4);
        unsigned int u2 = *(const unsigned int*)(hr + 8);
        dec4_fma(u0, sn, acc); dec4_fma(u1, sn, acc + 4); dec4_fma(u2, sn, acc + 8);
    }
    int e0 = start[wid], e1 = start[wid + 1];
    int e = e0;
    for (; e + 8 <= e1; e += 8){
        int s[8]; float nm[8]; unsigned int u[8][3];
        #pragma unroll
        for (int b = 0; b < 8; b++){ s[b] = csr_src[e + b]; nm[b] = csr_norm[e + b]; }
        #pragma unroll
        for (int b = 0; b < 8; b++){
            const unsigned char* hs = h8 + (size_t)s[b] * D + lo;
            u[b][0] = *(const unsigned int*)(hs);
            u[b][1] = *(const unsigned int*)(hs + 4);
            u[b][2] = *(const unsigned int*)(hs + 8);
        }
        #pragma unroll
        for (int b = 0; b < 8; b++){
            dec4_fma(u[b][0], nm[b], acc);
            dec4_fma(u[b][1], nm[b], acc + 4);
            dec4_fma(u[b][2], nm[b], acc + 8);
        }
    }
    for (; e < e1; e++){
        int s = csr_src[e];
        float nm = csr_norm[e];
        const unsigned char* hs = h8 + (size_t)s * D + lo;
        unsigned int u0 = *(const unsigned int*)(hs);
        unsigned int u1 = *(const unsigned int*)(hs + 4);
        unsigned int u2 = *(const unsigned int*)(hs + 8);
        dec4_fma(u0, nm, acc); dec4_fma(u1, nm, acc + 4); dec4_fma(u2, nm, acc + 8);
    }
    float r[12];
    #pragma unroll
    for (int i = 0; i < 12; i++){
        float t = acc[i] + bias[lo + i];
        if (doRelu) t = fmaxf(t, 0.0f);
        r[i] = t;
    }
    if constexpr (OUT8){
        unsigned char* orow = (unsigned char*)out + (size_t)wid * D + lo;
        #pragma unroll
        for (int j = 0; j < 3; j++)
            *(unsigned int*)(orow + j * 4) = pk4_fp8(r[j*4], r[j*4+1], r[j*4+2], r[j*4+3]);
    } else {
        unsigned short* orow = (unsigned short*)out + (size_t)wid * D + lo;
        #pragma unroll
        for (int j = 0; j < 3; j++){
            unsigned long long packed =
                (unsigned long long)f2b(r[j*4+0]) |
                ((unsigned long long)f2b(r[j*4+1]) << 16) |
                ((unsigned long long)f2b(r[j*4+2]) << 32) |
                ((unsigned long long)f2b(r[j*4+3]) << 48);
            __builtin_nontemporal_store(packed, (unsigned long long*)(orow + j * 4));
        }
    }
}

// ---------------- mark candidate rows + their in-neighbors ----------------
__global__ __launch_bounds__(256) void mark_rows(const int* __restrict__ cand,
                                                 const int* __restrict__ start,
                                                 const int* __restrict__ csr_src,
                                                 int* __restrict__ flag, int M){
    int i = blockIdx.x * 4 + (threadIdx.x >> 6);
    if (i >= M) return;
    int lane = threadIdx.x & 63;
    int c = cand[i];
    if (lane == 0) flag[c] = 1;
    int e0 = start[c], e1 = start[c + 1];
    for (int e = e0 + lane; e < e1; e += 64) flag[csr_src[e]] = 1;
}
__global__ __launch_bounds__(256) void compact_rows(const int* __restrict__ flag,
                                                    int* __restrict__ RL, int* rc, int N){
    int i = blockIdx.x * 256 + threadIdx.x;
    if (i < N && flag[i]) RL[atomicAdd(rc, 1)] = i;
}

// ---------------- approx bert score via fp8 MFMA ----------------
__global__ __launch_bounds__(256) void mfma_bert8(const unsigned char* __restrict__ Q8,
                                                  const unsigned char* __restrict__ X8,
                                                  const float* __restrict__ sparse,
                                                  const float* __restrict__ swp,
                                                  float* __restrict__ scoreOut,
                                                  int B, int N){
    __shared__ unsigned char Al[64 * 32];
    __shared__ unsigned char Bl[128 * 32];
    const int tid  = threadIdx.x;
    const int lane = tid & 63;
    const int w    = tid >> 6;
    const int l15  = lane & 15;
    const int lg   = lane >> 4;
    const int n0   = blockIdx.x * 128;

    const int ga    = tid;
    const int arow  = ga >> 1;
    const int ahalf = (ga & 1) * 16;
    const int gb    = w * 64 + lane;
    const int brow  = gb >> 1;
    const int bhalf = (gb & 1) * 16;

    f32x4 acc[4][2] = {};

    for (int k0 = 0; k0 < D; k0 += 32){
        if (w < 2)
            gload_lds16(Q8 + (size_t)arow * D + k0 + ahalf, (char*)Al + w * 1024);
        gload_lds16(X8 + (size_t)(n0 + brow) * D + k0 + bhalf, (char*)Bl + w * 1024);
        __syncthreads();
        long af[4], bfv[2];
        #pragma unroll
        for (int mf = 0; mf < 4; mf++)
            af[mf] = *(const long*)(&Al[(mf * 16 + l15) * 32 + lg * 8]);
        #pragma unroll
        for (int nf = 0; nf < 2; nf++)
            bfv[nf] = *(const long*)(&Bl[(w * 32 + nf * 16 + l15) * 32 + lg * 8]);
        #pragma unroll
        for (int mf = 0; mf < 4; mf++)
            #pragma unroll
            for (int nf = 0; nf < 2; nf++)
                acc[mf][nf] = __builtin_amdgcn_mfma_f32_16x16x32_fp8_fp8(af[mf], bfv[nf], acc[mf][nf], 0, 0, 0);
        __syncthreads();
    }
    float sw = swp[0];
    #pragma unroll
    for (int mf = 0; mf < 4; mf++){
        #pragma unroll
        for (int nf = 0; nf < 2; nf++){
            #pragma unroll
            for (int r = 0; r < 4; r++){
                int q = mf * 16 + lg * 4 + r;
                int n = n0 + w * 32 + nf * 16 + l15;
                if (q < B && n < N)
                    scoreOut[(size_t)q * N + n] = sw * sparse[(size_t)q * N + n] + acc[mf][nf][r];
            }
        }
    }
}

// ---------------- filter: per-(query,chunk) local top-CPC ----------------
__global__ __launch_bounds__(256) void filter_topc(const float* __restrict__ score,
                                                   int* __restrict__ candIdx,
                                                   int N, int chunk){
    int b = blockIdx.y, g = blockIdx.x, tid = threadIdx.x;
    int base = g * chunk;
    const float* s = score + (size_t)b * N;
    extern __shared__ float vals[];
    for (int i = tid; i < chunk; i += 256){
        int n = base + i;
        vals[i] = (n < N) ? s[n] : -3.0e38f;
    }
    __shared__ float wv[4];
    __shared__ int   wsl[4];
    __syncthreads();
    int lane = tid & 63, wid = tid >> 6;
    int* out = candIdx + ((size_t)b * gridDim.x + g) * CPC;
    for (int it = 0; it < CPC; it++){
        float best = -3.0e38f; int bs = 0x7fffffff;
        for (int i = tid; i < chunk; i += 256){
            float v = vals[i];
            if (v > best){ best = v; bs = i; }
        }
        #pragma unroll
        for (int o = 32; o > 0; o >>= 1){
            float v2 = __shfl_down(best, o);
            int   s2 = __shfl_down(bs, o);
            if (v2 > best || (v2 == best && s2 < bs)){ best = v2; bs = s2; }
        }
        if (lane == 0){ wv[wid] = best; wsl[wid] = bs; }
        __syncthreads();
        if (tid == 0){
            float bv = wv[0]; int bi = wsl[0];
            #pragma unroll
            for (int w2 = 1; w2 < 4; w2++)
                if (wv[w2] > bv || (wv[w2] == bv && wsl[w2] < bi)){ bv = wv[w2]; bi = wsl[w2]; }
            out[it] = base + bi;
            if (bi >= 0 && bi < chunk) vals[bi] = -3.0e38f;
        }
        __syncthreads();
    }
}

// ---------------- exact fp32 rescore ----------------
__global__ __launch_bounds__(256) void rescore_kernel(const float* __restrict__ Q,
                                                      const float* __restrict__ X,
                                                      const float* __restrict__ sparse,
                                                      const float* __restrict__ swp,
                                                      const int* __restrict__ candIdx,
                                                      float* __restrict__ resVal,
                                                      int N){
    int b = blockIdx.y;
    int c0 = blockIdx.x * 64;
    int lane = threadIdx.x & 63, w = threadIdx.x >> 6;
    const float* q = Q + (size_t)b * D;
    f32x4 qv[3];
    #pragma unroll
    for (int j = 0; j < 3; j++) qv[j] = *(const f32x4*)(q + lane * 4 + 256 * j);
    float sw = swp[0];
    for (int t = 0; t < 16; t++){
        int ci = c0 + w * 16 + t;
        int n = candIdx[(size_t)b * NCAND + ci];
        const float* x = X + (size_t)n * D;
        float sum = 0.0f;
        #pragma unroll
        for (int j = 0; j < 3; j++){
            f32x4 xv = *(const f32x4*)(x + lane * 4 + 256 * j);
            sum += qv[j][0]*xv[0] + qv[j][1]*xv[1] + qv[j][2]*xv[2] + qv[j][3]*xv[3];
        }
        #pragma unroll
        for (int o = 32; o > 0; o >>= 1) sum += __shfl_down(sum, o);
        if (lane == 0)
            resVal[(size_t)b * NCAND + ci] = sw * sparse[(size_t)b * N + n] + sum;
    }
}

// ---------------- exact top-K among NCAND rescored + gold forcing ----------------
__global__ __launch_bounds__(256) void select_topk(const float* __restrict__ resVal,
                                                   const int* __restrict__ candIdx,
                                                   const int* __restrict__ qidx,
                                                   int* __restrict__ cand,
                                                   float* __restrict__ outIdx,
                                                   int K){
    int b = blockIdx.x, tid = threadIdx.x;
    __shared__ float vals[NCAND];
    __shared__ int   gidx[NCAND];
    __shared__ int   csel[64];
    __shared__ float wv[4];
    __shared__ int   wi[4];
    __shared__ int   wsl[4];
    vals[tid] = resVal[(size_t)b * NCAND + tid];
    gidx[tid] = candIdx[(size_t)b * NCAND + tid];
    __syncthreads();
    int lane = tid & 63, wid = tid >> 6;
    for (int it = 0; it < K; it++){
        float best = vals[tid]; int bg = gidx[tid]; int bsl = tid;
        #pragma unroll
        for (int o = 32; o > 0; o >>= 1){
            float v2 = __shfl_down(best, o);
            int   g2 = __shfl_down(bg, o);
            int   s2 = __shfl_down(bsl, o);
            if (v2 > best || (v2 == best && g2 < bg)){ best = v2; bg = g2; bsl = s2; }
        }
        if (lane == 0){ wv[wid] = best; wi[wid] = bg; wsl[wid] = bsl; }
        __syncthreads();
        if (tid == 0){
            float bv = wv[0]; int bi = wi[0]; int sl = wsl[0];
            #pragma unroll
            for (int w2 = 1; w2 < 4; w2++)
                if (wv[w2] > bv || (wv[w2] == bv && wi[w2] < bi)){ bv = wv[w2]; bi = wi[w2]; sl = wsl[w2]; }
            csel[it] = bi;
            vals[sl] = -3.0e38f;
        }
        __syncthreads();
    }
    if (tid == 0){
        int qi = qidx[b];
        bool has = false;
        for (int k2 = 0; k2 < K; k2++) if (csel[k2] == qi) has = true;
        if (!has) csel[K - 1] = qi;
    }
    __syncthreads();
    if (tid < K){
        cand[b * K + tid]   = csel[tid];
        outIdx[b * K + tid] = (float)csel[tid];
    }
}

// ---------------- final scoring head ----------------
__global__ __launch_bounds__(256) void final_kernel(const unsigned short* __restrict__ emb,
                                                    const float* __restrict__ Q,
                                                    const int* __restrict__ cand,
                                                    const float* __restrict__ scoreW,
                                                    const float* __restrict__ scoreB,
                                                    float* __restrict__ out, int B, int K){
    int pair = blockIdx.x * 4 + (threadIdx.x >> 6);
    if (pair >= B * K) return;
    int lane = threadIdx.x & 63;
    int b = pair / K;
    int c = cand[pair];
    const unsigned short* g = emb + (size_t)c * D;
    const float* q = Q + (size_t)b * D;
    float sum = 0.0f;
    #pragma unroll
    for (int j = 0; j < 12; j++){
        int col = lane + 64 * j;
        sum += b2f(g[col]) * scoreW[col] + q[col] * scoreW[D + col];
    }
    #pragma unroll
    for (int o = 32; o > 0; o >>= 1) sum += __shfl_down(sum, o);
    if (lane == 0) out[pair] = fmaxf(sum + scoreB[0], 0.0f);
}

extern "C" void kernel_launch(void* const* d_in, const int* in_sizes, int n_in,
                              void* d_out, int out_size, void* d_ws, size_t ws_size,
                              hipStream_t stream){
    const float* q_emb   = (const float*)d_in[0];
    const float* x_emb   = (const float*)d_in[1];
    const float* sparse  = (const float*)d_in[2];
    const int*   q_idx   = (const int*)d_in[3];
    const int*   eidx    = (const int*)d_in[4];
    const float* sweight = (const float*)d_in[5];
    const float* W1      = (const float*)d_in[6];
    const float* b1      = (const float*)d_in[7];
    const float* W2      = (const float*)d_in[8];
    const float* b2      = (const float*)d_in[9];
    const float* scoreW  = (const float*)d_in[10];
    const float* scoreB  = (const float*)d_in[11];

    const int B = in_sizes[0] / D;
    const int N = in_sizes[1] / D;
    const int E = in_sizes[4] / 2;
    const int K = out_size / (2 * B);

    const int* esrc = eidx;
    const int* edst = eidx + E;

    char* ws = (char*)d_ws;
    size_t off = 0;
    auto alloc = [&](size_t bytes) -> char* {
        char* p = ws + off;
        off = (off + bytes + 255) & ~(size_t)255;
        return p;
    };
    unsigned char*  bufX8 = (unsigned char*)alloc((size_t)(N + 128) * D);    // x fp8 (gemm-1 A, bert X)
    unsigned char*  bufH8 = (unsigned char*)alloc((size_t)(N + 128) * D);    // h fp8 (gemm out, agg in)
    unsigned char*  bufG8 = (unsigned char*)alloc((size_t)(N + 128) * D);    // g1 fp8 (gemm-2 A, RL rows)
    unsigned short* bufG  = (unsigned short*)alloc((size_t)N * D * 2);       // final emb bf16 (cand rows)
    unsigned char*  Qb8   = (unsigned char*)alloc((size_t)(B + 64) * D);     // query fp8
    unsigned char*  W1t8  = (unsigned char*)alloc((size_t)D * D);
    unsigned char*  W2t8  = (unsigned char*)alloc((size_t)D * D);
    int*   cnt   = (int*)alloc((size_t)N * 4);
    float* dis   = (float*)alloc((size_t)N * 4);
    int*   start = (int*)alloc((size_t)(N + 1) * 4);
    int*   fill  = (int*)alloc((size_t)N * 4);
    int*   bsum  = (int*)alloc(1024);
    int*   boff  = (int*)alloc(1024);
    int*   csrs  = (int*)alloc((size_t)E * 4);
    float* csrn  = (float*)alloc((size_t)E * 4);
    float* approxScore = (float*)alloc((size_t)B * N * 4);
    int*   candIdx = (int*)alloc((size_t)B * NCAND * 4);
    float* resVal  = (float*)alloc((size_t)B * NCAND * 4);
    int*   candBuf = (int*)alloc((size_t)B * K * 4);
    int*   flag    = (int*)alloc((size_t)N * 4);
    int*   RL      = (int*)alloc((size_t)(N + 128) * 4);
    int*   rcp     = (int*)alloc(256);
    (void)ws_size; (void)n_in;

    float* outScore = (float*)d_out;
    float* outIdx   = outScore + (size_t)B * K;

    // 1. conversions: x+q -> fp8 in one dispatch; both weight transposes in one dispatch
    size_t nxq = (size_t)N * D / 4;
    size_t nqq = (size_t)B * D / 4;
    cvt8_fused<<<(unsigned)((nxq + nqq + 255) / 256), 256, 0, stream>>>(x_emb, bufX8, nxq, q_emb, Qb8, nqq);
    dim3 tg(D / 32, D / 32, 2);
    transposeW8<<<tg, 256, 0, stream>>>(W1, W1t8, W2, W2t8);

    // 2. prep (zero cnt/flag/rcp) + degree + CSR
    int nb = (N + 255) / 256;
    prep_zero<<<nb, 256, 0, stream>>>(cnt, flag, rcp, N);
    deg_count<<<(E + 255) / 256, 256, 0, stream>>>(edst, cnt, E);
    dis_blocksum<<<nb, 256, 0, stream>>>(cnt, dis, bsum, N);
    scanb_k<<<1, 256, 0, stream>>>(bsum, boff, nb);
    scanfin_k<<<nb, 256, 0, stream>>>(cnt, boff, start, fill, N, E);
    csr_fill<<<(E + 255) / 256, 256, 0, stream>>>(esrc, edst, dis, start, fill, csrs, csrn, E);

    // 3. retrieval FIRST: fp8 approx -> filter -> exact fp32 rescore -> top-K
    mfma_bert8<<<(N + 127) / 128, 256, 0, stream>>>(Qb8, bufX8, sparse, sweight, approxScore, B, N);
    int chunk = (N + FCH - 1) / FCH;
    dim3 fgrid(FCH, B);
    filter_topc<<<fgrid, 256, (size_t)chunk * 4, stream>>>(approxScore, candIdx, N, chunk);
    dim3 rgrid(NCAND / 64, B);
    rescore_kernel<<<rgrid, 256, 0, stream>>>(q_emb, x_emb, sparse, sweight, candIdx, resVal, N);
    select_topk<<<B, 256, 0, stream>>>(resVal, candIdx, q_idx, candBuf, outIdx, K);

    // 4. mark candidate rows + in-neighbors; compact to RL
    mark_rows<<<(B * K + 3) / 4, 256, 0, stream>>>(candBuf, start, csrs, flag, B * K);
    compact_rows<<<nb, 256, 0, stream>>>(flag, RL, rcp, N);

    // 5. GCN layer 1: full GEMM (h1 needed at ~all rows), agg only at RL rows
    const int nTilesM = (N + 127) / 128;
    const int nTilesN = D / 128;             // 6
    const int gemmWG  = nTilesM * nTilesN;
    gemm_fp8<<<gemmWG, 256, 0, stream>>>(bufX8, W1t8, bufH8, N, nTilesN);
    agg_fp8<true, true><<<(N + 3) / 4, 256, 0, stream>>>(bufH8, bufG8, start, csrs, csrn, dis, b1, RL, rcp, 1, N);

    // 6. GCN layer 2, sparse: h2 only at RL rows; agg only at candidate rows
    gemm_fp8_list<<<gemmWG, 256, 0, stream>>>(bufG8, W2t8, bufH8, RL, rcp, nTilesN);
    agg_fp8<false, true><<<(B * K + 3) / 4, 256, 0, stream>>>(bufH8, bufG, start, csrs, csrn, dis, b2, candBuf, nullptr, 0, B * K);

    // 7. final scoring head
    final_kernel<<<(B * K + 3) / 4, 256, 0, stream>>>(bufG, q_emb, candBuf, scoreW, scoreB, outScore, B, K);
}

// Round 15
// 399.273 us; speedup vs baseline: 1.1181x; 1.1181x over previous
//
#include <hip/hip_runtime.h>
#include <stdint.h>

#define D 768
#define FCH 16     // filter chunks per query
#define CPC 16     // candidates kept per chunk
#define NCAND 256  // FCH * CPC

typedef __bf16 bf16x8 __attribute__((ext_vector_type(8)));
typedef float  f32x4  __attribute__((ext_vector_type(4)));
typedef float  f32x2  __attribute__((ext_vector_type(2)));

static __device__ __forceinline__ float b2f(unsigned short u){
    union { unsigned int i; float f; } v; v.i = ((unsigned int)u) << 16; return v.f;
}
static __device__ __forceinline__ unsigned short f2b(float f){
    union { float f; unsigned int i; } v; v.f = f;
    unsigned int u = v.i;
    unsigned int r = (u + 0x7fffu + ((u >> 16) & 1u)) >> 16;
    return (unsigned short)r;
}
static __device__ __forceinline__ void gload_lds16(const void* g, void* l){
    __builtin_amdgcn_global_load_lds((const __attribute__((address_space(1))) void*)g,
                                     (__attribute__((address_space(3))) void*)l, 16, 0, 0);
}
static __device__ __forceinline__ void dec4_fma(unsigned int u, float nm, float* acc){
    f32x2 a = __builtin_amdgcn_cvt_pk_f32_fp8((int)u, false);
    f32x2 b = __builtin_amdgcn_cvt_pk_f32_fp8((int)u, true);
    acc[0] += a[0] * nm; acc[1] += a[1] * nm;
    acc[2] += b[0] * nm; acc[3] += b[1] * nm;
}
static __device__ __forceinline__ unsigned char f2fp8(float f){
    int p = __builtin_amdgcn_cvt_pk_fp8_f32(f, 0.0f, 0, false);
    return (unsigned char)(p & 0xFF);
}
static __device__ __forceinline__ unsigned int pk4_fp8(float a, float b, float c, float d){
    int lo = __builtin_amdgcn_cvt_pk_fp8_f32(a, b, 0, false);
    int fu = __builtin_amdgcn_cvt_pk_fp8_f32(c, d, lo, true);
    return (unsigned int)fu;
}

// ---------------- fused f32 -> fp8 conversion for x and q ----------------
__global__ __launch_bounds__(256) void cvt8_fused(const float* __restrict__ x,
                                                  unsigned char* __restrict__ y8, size_t nxq,
                                                  const float* __restrict__ qq,
                                                  unsigned char* __restrict__ q8, size_t nqq){
    size_t i = (size_t)blockIdx.x * 256 + threadIdx.x;   // quad index
    if (i < nxq){
        f32x4 v = *(const f32x4*)(x + i * 4);
        *(unsigned int*)(y8 + i * 4) = pk4_fp8(v[0], v[1], v[2], v[3]);
    } else if (i - nxq < nqq){
        size_t j = i - nxq;
        f32x4 v = *(const f32x4*)(qq + j * 4);
        *(unsigned int*)(q8 + j * 4) = pk4_fp8(v[0], v[1], v[2], v[3]);
    }
}

// ---------------- W [D][D] f32 -> Wt [n][k] fp8 (both weights, z-indexed) ----------------
__global__ __launch_bounds__(256) void transposeW8(const float* __restrict__ W1,
                                                   unsigned char* __restrict__ W1t,
                                                   const float* __restrict__ W2,
                                                   unsigned char* __restrict__ W2t){
    const float* W = blockIdx.z ? W2 : W1;
    unsigned char* Wt = blockIdx.z ? W2t : W1t;
    __shared__ unsigned char tile[32][33];
    int bx = blockIdx.x * 32;   // k base
    int by = blockIdx.y * 32;   // n base
    int tx = threadIdx.x & 31, ty = threadIdx.x >> 5;
    #pragma unroll
    for (int r = 0; r < 32; r += 8)
        tile[ty + r][tx] = f2fp8(W[(size_t)(bx + ty + r) * D + by + tx]);
    __syncthreads();
    #pragma unroll
    for (int r = 0; r < 32; r += 8)
        Wt[(size_t)(by + ty + r) * D + bx + tx] = tile[tx][ty + r];
}

// ---------------- prep: zero cnt, flag, rcp in one dispatch ----------------
__global__ __launch_bounds__(256) void prep_zero(int* __restrict__ cnt, int* __restrict__ flag,
                                                 int* __restrict__ rcp, int N){
    int i = blockIdx.x * 256 + threadIdx.x;
    if (i < N){ cnt[i] = 0; flag[i] = 0; }
    if (i == 0) rcp[0] = 0;
}

// ---------------- degree / dis / CSR ----------------
__global__ __launch_bounds__(256) void deg_count(const int* __restrict__ dst, int* cnt, int E){
    int e = blockIdx.x * 256 + threadIdx.x;
    if (e < E) atomicAdd(&cnt[dst[e]], 1);
}
__global__ __launch_bounds__(256) void dis_blocksum(const int* __restrict__ cnt,
                                                    float* __restrict__ dis,
                                                    int* __restrict__ bsum, int N){
    __shared__ int sm[256];
    int tid = threadIdx.x;
    int i = blockIdx.x * 256 + tid;
    int c = (i < N) ? cnt[i] : 0;
    if (i < N) dis[i] = rsqrtf((float)(c + 1));
    sm[tid] = c;
    __syncthreads();
    for (int o = 128; o > 0; o >>= 1){
        if (tid < o) sm[tid] += sm[tid + o];
        __syncthreads();
    }
    if (tid == 0) bsum[blockIdx.x] = sm[0];
}
__global__ __launch_bounds__(256) void scanb_k(const int* __restrict__ bsum, int* boff, int nb){
    __shared__ int sm[256];
    int tid = threadIdx.x;
    int v = (tid < nb) ? bsum[tid] : 0;
    sm[tid] = v;
    __syncthreads();
    for (int o = 1; o < 256; o <<= 1){
        int add = (tid >= o) ? sm[tid - o] : 0;
        __syncthreads();
        sm[tid] += add;
        __syncthreads();
    }
    if (tid < nb) boff[tid] = sm[tid] - v;
}
__global__ __launch_bounds__(256) void scanfin_k(const int* __restrict__ cnt,
                                                 const int* __restrict__ boff,
                                                 int* start, int* fill, int N, int E){
    __shared__ int sm[256];
    int tid = threadIdx.x;
    int i = blockIdx.x * 256 + tid;
    int v = (i < N) ? cnt[i] : 0;
    sm[tid] = v;
    __syncthreads();
    for (int o = 1; o < 256; o <<= 1){
        int add = (tid >= o) ? sm[tid - o] : 0;
        __syncthreads();
        sm[tid] += add;
        __syncthreads();
    }
    if (i < N){ start[i] = boff[blockIdx.x] + sm[tid] - v; fill[i] = 0; }
    if (i == 0) start[N] = E;
}
__global__ __launch_bounds__(256) void csr_fill(const int* __restrict__ src,
                                                const int* __restrict__ dst,
                                                const float* __restrict__ dis,
                                                const int* __restrict__ start,
                                                int* fill, int* csr_src, float* csr_norm, int E){
    int e = blockIdx.x * 256 + threadIdx.x;
    if (e >= E) return;
    int s = src[e], d = dst[e];
    int pos = atomicAdd(&fill[d], 1);
    int idx = start[d] + pos;
    csr_src[idx]  = s;
    csr_norm[idx] = dis[s] * dis[d];
}

// ---------------- fp8 MFMA GEMM (full M): C = A8[M][768] @ W8, fp8 out ----------------
// BK=32, linear [128][32]-byte LDS tiles, ONE gload_lds16 per matrix per K-step (R13-proven).
__global__ __launch_bounds__(256) void gemm_fp8(const unsigned char* __restrict__ A,
                                                const unsigned char* __restrict__ Bt,
                                                unsigned char* __restrict__ Cout,
                                                int M, int nTilesN){
    __shared__ unsigned char Al[128 * 32];
    __shared__ unsigned char Bl[128 * 32];
    const int nwg = gridDim.x;
    const int bid = blockIdx.x;
    const int q = nwg >> 3, r = nwg & 7;
    const int xcd = bid & 7, loc = bid >> 3;
    const int swz = (xcd < r ? xcd * (q + 1) : r * (q + 1) + (xcd - r) * q) + loc;
    const int mt = swz / nTilesN, nt = swz % nTilesN;
    const int m0 = mt * 128, n0 = nt * 128;

    const int tid  = threadIdx.x;
    const int lane = tid & 63;
    const int w    = tid >> 6;
    const int wr = w >> 1, wc = w & 1;
    const int l15 = lane & 15;
    const int lg  = lane >> 4;

    const int g     = w * 64 + lane;
    const int srow  = g >> 1;
    const int shalf = (g & 1) * 16;

    f32x4 acc[4][4] = {};

    for (int k0 = 0; k0 < D; k0 += 32){
        gload_lds16(A  + (size_t)(m0 + srow) * D + k0 + shalf, (char*)Al + w * 1024);
        gload_lds16(Bt + (size_t)(n0 + srow) * D + k0 + shalf, (char*)Bl + w * 1024);
        __syncthreads();
        long af[4], bfv[4];
        #pragma unroll
        for (int mf = 0; mf < 4; mf++)
            af[mf] = *(const long*)(&Al[(wr * 64 + mf * 16 + l15) * 32 + lg * 8]);
        #pragma unroll
        for (int nf = 0; nf < 4; nf++)
            bfv[nf] = *(const long*)(&Bl[(wc * 64 + nf * 16 + l15) * 32 + lg * 8]);
        #pragma unroll
        for (int mf = 0; mf < 4; mf++)
            #pragma unroll
            for (int nf = 0; nf < 4; nf++)
                acc[mf][nf] = __builtin_amdgcn_mfma_f32_16x16x32_fp8_fp8(af[mf], bfv[nf], acc[mf][nf], 0, 0, 0);
        __syncthreads();
    }
    #pragma unroll
    for (int mf = 0; mf < 4; mf++){
        #pragma unroll
        for (int r2 = 0; r2 < 4; r2++){
            int gr = m0 + wr * 64 + mf * 16 + lg * 4 + r2;
            if (gr < M){
                #pragma unroll
                for (int nf = 0; nf < 4; nf++){
                    int gc = n0 + wc * 64 + nf * 16 + l15;
                    Cout[(size_t)gr * D + gc] = f2fp8(acc[mf][nf][r2]);
                }
            }
        }
    }
}

// ---------------- row-list fp8 GEMM (BK=32): C[RL[i]] = A8[RL[i]] @ W8 for i < *rcp ----------
__global__ __launch_bounds__(256) void gemm_fp8_list(const unsigned char* __restrict__ A,
                                                     const unsigned char* __restrict__ Bt,
                                                     unsigned char* __restrict__ Cout,
                                                     const int* __restrict__ RL,
                                                     const int* __restrict__ rcp,
                                                     int nTilesN){
    const int rc = *rcp;
    __shared__ unsigned char Al[128 * 32];
    __shared__ unsigned char Bl[128 * 32];
    __shared__ int rlTile[128];
    const int nwg = gridDim.x;
    const int bid = blockIdx.x;
    const int q = nwg >> 3, r = nwg & 7;
    const int xcd = bid & 7, loc = bid >> 3;
    const int swz = (xcd < r ? xcd * (q + 1) : r * (q + 1) + (xcd - r) * q) + loc;
    const int mt = swz / nTilesN, nt = swz % nTilesN;
    const int m0 = mt * 128, n0 = nt * 128;
    if (m0 >= rc) return;

    const int tid  = threadIdx.x;
    if (tid < 128){
        int p = m0 + tid;
        rlTile[tid] = RL[p < rc ? p : rc - 1];
    }
    const int lane = tid & 63;
    const int w    = tid >> 6;
    const int wr = w >> 1, wc = w & 1;
    const int l15 = lane & 15;
    const int lg  = lane >> 4;

    const int g     = w * 64 + lane;
    const int srow  = g >> 1;
    const int shalf = (g & 1) * 16;
    __syncthreads();
    const int arow = rlTile[srow];

    f32x4 acc[4][4] = {};

    for (int k0 = 0; k0 < D; k0 += 32){
        gload_lds16(A  + (size_t)arow * D + k0 + shalf, (char*)Al + w * 1024);
        gload_lds16(Bt + (size_t)(n0 + srow) * D + k0 + shalf, (char*)Bl + w * 1024);
        __syncthreads();
        long af[4], bfv[4];
        #pragma unroll
        for (int mf = 0; mf < 4; mf++)
            af[mf] = *(const long*)(&Al[(wr * 64 + mf * 16 + l15) * 32 + lg * 8]);
        #pragma unroll
        for (int nf = 0; nf < 4; nf++)
            bfv[nf] = *(const long*)(&Bl[(wc * 64 + nf * 16 + l15) * 32 + lg * 8]);
        #pragma unroll
        for (int mf = 0; mf < 4; mf++)
            #pragma unroll
            for (int nf = 0; nf < 4; nf++)
                acc[mf][nf] = __builtin_amdgcn_mfma_f32_16x16x32_fp8_fp8(af[mf], bfv[nf], acc[mf][nf], 0, 0, 0);
        __syncthreads();
    }
    #pragma unroll
    for (int mf = 0; mf < 4; mf++){
        #pragma unroll
        for (int r2 = 0; r2 < 4; r2++){
            int lr = wr * 64 + mf * 16 + lg * 4 + r2;
            if (m0 + lr < rc){
                int gr = rlTile[lr];
                #pragma unroll
                for (int nf = 0; nf < 4; nf++){
                    int gc = n0 + wc * 64 + nf * 16 + l15;
                    Cout[(size_t)gr * D + gc] = f2fp8(acc[mf][nf][r2]);
                }
            }
        }
    }
}

// ---------------- GCN aggregation (fp8 gather). LIST: rows from list; Mp: device count ----
template<bool OUT8, bool LIST>
__global__ __launch_bounds__(256) void agg_fp8(const unsigned char* __restrict__ h8,
                                               void* __restrict__ out,
                                               const int* __restrict__ start,
                                               const int* __restrict__ csr_src,
                                               const float* __restrict__ csr_norm,
                                               const float* __restrict__ dis,
                                               const float* __restrict__ bias,
                                               const int* __restrict__ list,
                                               const int* __restrict__ Mp,
                                               int doRelu, int M){
    if (Mp) M = *Mp;
    int pair = blockIdx.x * 4 + (threadIdx.x >> 6);
    if (pair >= M) return;
    int wid = LIST ? list[pair] : pair;
    int lane = threadIdx.x & 63;
    const int lo = lane * 12;
    float acc[12] = {};
    float dn = dis[wid];
    float sn = dn * dn;
    {
        const unsigned char* hr = h8 + (size_t)wid * D + lo;
        unsigned int u0 = *(const unsigned int*)(hr);
        unsigned int u1 = *(const unsigned int*)(hr + 4);
        unsigned int u2 = *(const unsigned int*)(hr + 8);
        dec4_fma(u0, sn, acc); dec4_fma(u1, sn, acc + 4); dec4_fma(u2, sn, acc + 8);
    }
    int e0 = start[wid], e1 = start[wid + 1];
    int e = e0;
    for (; e + 8 <= e1; e += 8){
        int s[8]; float nm[8]; unsigned int u[8][3];
        #pragma unroll
        for (int b = 0; b < 8; b++){ s[b] = csr_src[e + b]; nm[b] = csr_norm[e + b]; }
        #pragma unroll
        for (int b = 0; b < 8; b++){
            const unsigned char* hs = h8 + (size_t)s[b] * D + lo;
            u[b][0] = *(const unsigned int*)(hs);
            u[b][1] = *(const unsigned int*)(hs + 4);
            u[b][2] = *(const unsigned int*)(hs + 8);
        }
        #pragma unroll
        for (int b = 0; b < 8; b++){
            dec4_fma(u[b][0], nm[b], acc);
            dec4_fma(u[b][1], nm[b], acc + 4);
            dec4_fma(u[b][2], nm[b], acc + 8);
        }
    }
    for (; e < e1; e++){
        int s = csr_src[e];
        float nm = csr_norm[e];
        const unsigned char* hs = h8 + (size_t)s * D + lo;
        unsigned int u0 = *(const unsigned int*)(hs);
        unsigned int u1 = *(const unsigned int*)(hs + 4);
        unsigned int u2 = *(const unsigned int*)(hs + 8);
        dec4_fma(u0, nm, acc); dec4_fma(u1, nm, acc + 4); dec4_fma(u2, nm, acc + 8);
    }
    float r[12];
    #pragma unroll
    for (int i = 0; i < 12; i++){
        float t = acc[i] + bias[lo + i];
        if (doRelu) t = fmaxf(t, 0.0f);
        r[i] = t;
    }
    if constexpr (OUT8){
        unsigned char* orow = (unsigned char*)out + (size_t)wid * D + lo;
        #pragma unroll
        for (int j = 0; j < 3; j++)
            *(unsigned int*)(orow + j * 4) = pk4_fp8(r[j*4], r[j*4+1], r[j*4+2], r[j*4+3]);
    } else {
        unsigned short* orow = (unsigned short*)out + (size_t)wid * D + lo;
        #pragma unroll
        for (int j = 0; j < 3; j++){
            unsigned long long packed =
                (unsigned long long)f2b(r[j*4+0]) |
                ((unsigned long long)f2b(r[j*4+1]) << 16) |
                ((unsigned long long)f2b(r[j*4+2]) << 32) |
                ((unsigned long long)f2b(r[j*4+3]) << 48);
            __builtin_nontemporal_store(packed, (unsigned long long*)(orow + j * 4));
        }
    }
}

// ---------------- mark candidate rows + their in-neighbors ----------------
__global__ __launch_bounds__(256) void mark_rows(const int* __restrict__ cand,
                                                 const int* __restrict__ start,
                                                 const int* __restrict__ csr_src,
                                                 int* __restrict__ flag, int M){
    int i = blockIdx.x * 4 + (threadIdx.x >> 6);
    if (i >= M) return;
    int lane = threadIdx.x & 63;
    int c = cand[i];
    if (lane == 0) flag[c] = 1;
    int e0 = start[c], e1 = start[c + 1];
    for (int e = e0 + lane; e < e1; e += 64) flag[csr_src[e]] = 1;
}
__global__ __launch_bounds__(256) void compact_rows(const int* __restrict__ flag,
                                                    int* __restrict__ RL, int* rc, int N){
    int i = blockIdx.x * 256 + threadIdx.x;
    if (i < N && flag[i]) RL[atomicAdd(rc, 1)] = i;
}

// ---------------- approx bert score via fp8 MFMA ----------------
__global__ __launch_bounds__(256) void mfma_bert8(const unsigned char* __restrict__ Q8,
                                                  const unsigned char* __restrict__ X8,
                                                  const float* __restrict__ sparse,
                                                  const float* __restrict__ swp,
                                                  float* __restrict__ scoreOut,
                                                  int B, int N){
    __shared__ unsigned char Al[64 * 32];
    __shared__ unsigned char Bl[128 * 32];
    const int tid  = threadIdx.x;
    const int lane = tid & 63;
    const int w    = tid >> 6;
    const int l15  = lane & 15;
    const int lg   = lane >> 4;
    const int n0   = blockIdx.x * 128;

    const int ga    = tid;
    const int arow  = ga >> 1;
    const int ahalf = (ga & 1) * 16;
    const int gb    = w * 64 + lane;
    const int brow  = gb >> 1;
    const int bhalf = (gb & 1) * 16;

    f32x4 acc[4][2] = {};

    for (int k0 = 0; k0 < D; k0 += 32){
        if (w < 2)
            gload_lds16(Q8 + (size_t)arow * D + k0 + ahalf, (char*)Al + w * 1024);
        gload_lds16(X8 + (size_t)(n0 + brow) * D + k0 + bhalf, (char*)Bl + w * 1024);
        __syncthreads();
        long af[4], bfv[2];
        #pragma unroll
        for (int mf = 0; mf < 4; mf++)
            af[mf] = *(const long*)(&Al[(mf * 16 + l15) * 32 + lg * 8]);
        #pragma unroll
        for (int nf = 0; nf < 2; nf++)
            bfv[nf] = *(const long*)(&Bl[(w * 32 + nf * 16 + l15) * 32 + lg * 8]);
        #pragma unroll
        for (int mf = 0; mf < 4; mf++)
            #pragma unroll
            for (int nf = 0; nf < 2; nf++)
                acc[mf][nf] = __builtin_amdgcn_mfma_f32_16x16x32_fp8_fp8(af[mf], bfv[nf], acc[mf][nf], 0, 0, 0);
        __syncthreads();
    }
    float sw = swp[0];
    #pragma unroll
    for (int mf = 0; mf < 4; mf++){
        #pragma unroll
        for (int nf = 0; nf < 2; nf++){
            #pragma unroll
            for (int r = 0; r < 4; r++){
                int q = mf * 16 + lg * 4 + r;
                int n = n0 + w * 32 + nf * 16 + l15;
                if (q < B && n < N)
                    scoreOut[(size_t)q * N + n] = sw * sparse[(size_t)q * N + n] + acc[mf][nf][r];
            }
        }
    }
}

// ---------------- filter: per-(query,chunk) local top-CPC ----------------
__global__ __launch_bounds__(256) void filter_topc(const float* __restrict__ score,
                                                   int* __restrict__ candIdx,
                                                   int N, int chunk){
    int b = blockIdx.y, g = blockIdx.x, tid = threadIdx.x;
    int base = g * chunk;
    const float* s = score + (size_t)b * N;
    extern __shared__ float vals[];
    for (int i = tid; i < chunk; i += 256){
        int n = base + i;
        vals[i] = (n < N) ? s[n] : -3.0e38f;
    }
    __shared__ float wv[4];
    __shared__ int   wsl[4];
    __syncthreads();
    int lane = tid & 63, wid = tid >> 6;
    int* out = candIdx + ((size_t)b * gridDim.x + g) * CPC;
    for (int it = 0; it < CPC; it++){
        float best = -3.0e38f; int bs = 0x7fffffff;
        for (int i = tid; i < chunk; i += 256){
            float v = vals[i];
            if (v > best){ best = v; bs = i; }
        }
        #pragma unroll
        for (int o = 32; o > 0; o >>= 1){
            float v2 = __shfl_down(best, o);
            int   s2 = __shfl_down(bs, o);
            if (v2 > best || (v2 == best && s2 < bs)){ best = v2; bs = s2; }
        }
        if (lane == 0){ wv[wid] = best; wsl[wid] = bs; }
        __syncthreads();
        if (tid == 0){
            float bv = wv[0]; int bi = wsl[0];
            #pragma unroll
            for (int w2 = 1; w2 < 4; w2++)
                if (wv[w2] > bv || (wv[w2] == bv && wsl[w2] < bi)){ bv = wv[w2]; bi = wsl[w2]; }
            out[it] = base + bi;
            if (bi >= 0 && bi < chunk) vals[bi] = -3.0e38f;
        }
        __syncthreads();
    }
}

// ---------------- exact fp32 rescore ----------------
__global__ __launch_bounds__(256) void rescore_kernel(const float* __restrict__ Q,
                                                      const float* __restrict__ X,
                                                      const float* __restrict__ sparse,
                                                      const float* __restrict__ swp,
                                                      const int* __restrict__ candIdx,
                                                      float* __restrict__ resVal,
                                                      int N){
    int b = blockIdx.y;
    int c0 = blockIdx.x * 64;
    int lane = threadIdx.x & 63, w = threadIdx.x >> 6;
    const float* q = Q + (size_t)b * D;
    f32x4 qv[3];
    #pragma unroll
    for (int j = 0; j < 3; j++) qv[j] = *(const f32x4*)(q + lane * 4 + 256 * j);
    float sw = swp[0];
    for (int t = 0; t < 16; t++){
        int ci = c0 + w * 16 + t;
        int n = candIdx[(size_t)b * NCAND + ci];
        const float* x = X + (size_t)n * D;
        float sum = 0.0f;
        #pragma unroll
        for (int j = 0; j < 3; j++){
            f32x4 xv = *(const f32x4*)(x + lane * 4 + 256 * j);
            sum += qv[j][0]*xv[0] + qv[j][1]*xv[1] + qv[j][2]*xv[2] + qv[j][3]*xv[3];
        }
        #pragma unroll
        for (int o = 32; o > 0; o >>= 1) sum += __shfl_down(sum, o);
        if (lane == 0)
            resVal[(size_t)b * NCAND + ci] = sw * sparse[(size_t)b * N + n] + sum;
    }
}

// ---------------- exact top-K among NCAND rescored + gold forcing ----------------
__global__ __launch_bounds__(256) void select_topk(const float* __restrict__ resVal,
                                                   const int* __restrict__ candIdx,
                                                   const int* __restrict__ qidx,
                                                   int* __restrict__ cand,
                                                   float* __restrict__ outIdx,
                                                   int K){
    int b = blockIdx.x, tid = threadIdx.x;
    __shared__ float vals[NCAND];
    __shared__ int   gidx[NCAND];
    __shared__ int   csel[64];
    __shared__ float wv[4];
    __shared__ int   wi[4];
    __shared__ int   wsl[4];
    vals[tid] = resVal[(size_t)b * NCAND + tid];
    gidx[tid] = candIdx[(size_t)b * NCAND + tid];
    __syncthreads();
    int lane = tid & 63, wid = tid >> 6;
    for (int it = 0; it < K; it++){
        float best = vals[tid]; int bg = gidx[tid]; int bsl = tid;
        #pragma unroll
        for (int o = 32; o > 0; o >>= 1){
            float v2 = __shfl_down(best, o);
            int   g2 = __shfl_down(bg, o);
            int   s2 = __shfl_down(bsl, o);
            if (v2 > best || (v2 == best && g2 < bg)){ best = v2; bg = g2; bsl = s2; }
        }
        if (lane == 0){ wv[wid] = best; wi[wid] = bg; wsl[wid] = bsl; }
        __syncthreads();
        if (tid == 0){
            float bv = wv[0]; int bi = wi[0]; int sl = wsl[0];
            #pragma unroll
            for (int w2 = 1; w2 < 4; w2++)
                if (wv[w2] > bv || (wv[w2] == bv && wi[w2] < bi)){ bv = wv[w2]; bi = wi[w2]; sl = wsl[w2]; }
            csel[it] = bi;
            vals[sl] = -3.0e38f;
        }
        __syncthreads();
    }
    if (tid == 0){
        int qi = qidx[b];
        bool has = false;
        for (int k2 = 0; k2 < K; k2++) if (csel[k2] == qi) has = true;
        if (!has) csel[K - 1] = qi;
    }
    __syncthreads();
    if (tid < K){
        cand[b * K + tid]   = csel[tid];
        outIdx[b * K + tid] = (float)csel[tid];
    }
}

// ---------------- final scoring head ----------------
__global__ __launch_bounds__(256) void final_kernel(const unsigned short* __restrict__ emb,
                                                    const float* __restrict__ Q,
                                                    const int* __restrict__ cand,
                                                    const float* __restrict__ scoreW,
                                                    const float* __restrict__ scoreB,
                                                    float* __restrict__ out, int B, int K){
    int pair = blockIdx.x * 4 + (threadIdx.x >> 6);
    if (pair >= B * K) return;
    int lane = threadIdx.x & 63;
    int b = pair / K;
    int c = cand[pair];
    const unsigned short* g = emb + (size_t)c * D;
    const float* q = Q + (size_t)b * D;
    float sum = 0.0f;
    #pragma unroll
    for (int j = 0; j < 12; j++){
        int col = lane + 64 * j;
        sum += b2f(g[col]) * scoreW[col] + q[col] * scoreW[D + col];
    }
    #pragma unroll
    for (int o = 32; o > 0; o >>= 1) sum += __shfl_down(sum, o);
    if (lane == 0) out[pair] = fmaxf(sum + scoreB[0], 0.0f);
}

extern "C" void kernel_launch(void* const* d_in, const int* in_sizes, int n_in,
                              void* d_out, int out_size, void* d_ws, size_t ws_size,
                              hipStream_t stream){
    const float* q_emb   = (const float*)d_in[0];
    const float* x_emb   = (const float*)d_in[1];
    const float* sparse  = (const float*)d_in[2];
    const int*   q_idx   = (const int*)d_in[3];
    const int*   eidx    = (const int*)d_in[4];
    const float* sweight = (const float*)d_in[5];
    const float* W1      = (const float*)d_in[6];
    const float* b1      = (const float*)d_in[7];
    const float* W2      = (const float*)d_in[8];
    const float* b2      = (const float*)d_in[9];
    const float* scoreW  = (const float*)d_in[10];
    const float* scoreB  = (const float*)d_in[11];

    const int B = in_sizes[0] / D;
    const int N = in_sizes[1] / D;
    const int E = in_sizes[4] / 2;
    const int K = out_size / (2 * B);

    const int* esrc = eidx;
    const int* edst = eidx + E;

    char* ws = (char*)d_ws;
    size_t off = 0;
    auto alloc = [&](size_t bytes) -> char* {
        char* p = ws + off;
        off = (off + bytes + 255) & ~(size_t)255;
        return p;
    };
    unsigned char*  bufX8 = (unsigned char*)alloc((size_t)(N + 128) * D);    // x fp8 (gemm-1 A, bert X)
    unsigned char*  bufH8 = (unsigned char*)alloc((size_t)(N + 128) * D);    // h fp8 (gemm out, agg in)
    unsigned char*  bufG8 = (unsigned char*)alloc((size_t)(N + 128) * D);    // g1 fp8 (gemm-2 A, RL rows)
    unsigned short* bufG  = (unsigned short*)alloc((size_t)N * D * 2);       // final emb bf16 (cand rows)
    unsigned char*  Qb8   = (unsigned char*)alloc((size_t)(B + 64) * D);     // query fp8
    unsigned char*  W1t8  = (unsigned char*)alloc((size_t)D * D);
    unsigned char*  W2t8  = (unsigned char*)alloc((size_t)D * D);
    int*   cnt   = (int*)alloc((size_t)N * 4);
    float* dis   = (float*)alloc((size_t)N * 4);
    int*   start = (int*)alloc((size_t)(N + 1) * 4);
    int*   fill  = (int*)alloc((size_t)N * 4);
    int*   bsum  = (int*)alloc(1024);
    int*   boff  = (int*)alloc(1024);
    int*   csrs  = (int*)alloc((size_t)E * 4);
    float* csrn  = (float*)alloc((size_t)E * 4);
    float* approxScore = (float*)alloc((size_t)B * N * 4);
    int*   candIdx = (int*)alloc((size_t)B * NCAND * 4);
    float* resVal  = (float*)alloc((size_t)B * NCAND * 4);
    int*   candBuf = (int*)alloc((size_t)B * K * 4);
    int*   flag    = (int*)alloc((size_t)N * 4);
    int*   RL      = (int*)alloc((size_t)(N + 128) * 4);
    int*   rcp     = (int*)alloc(256);
    (void)ws_size; (void)n_in;

    float* outScore = (float*)d_out;
    float* outIdx   = outScore + (size_t)B * K;

    // 1. conversions: x+q -> fp8 in one dispatch; both weight transposes in one dispatch
    size_t nxq = (size_t)N * D / 4;
    size_t nqq = (size_t)B * D / 4;
    cvt8_fused<<<(unsigned)((nxq + nqq + 255) / 256), 256, 0, stream>>>(x_emb, bufX8, nxq, q_emb, Qb8, nqq);
    dim3 tg(D / 32, D / 32, 2);
    transposeW8<<<tg, 256, 0, stream>>>(W1, W1t8, W2, W2t8);

    // 2. prep (zero cnt/flag/rcp) + degree + CSR
    int nb = (N + 255) / 256;
    prep_zero<<<nb, 256, 0, stream>>>(cnt, flag, rcp, N);
    deg_count<<<(E + 255) / 256, 256, 0, stream>>>(edst, cnt, E);
    dis_blocksum<<<nb, 256, 0, stream>>>(cnt, dis, bsum, N);
    scanb_k<<<1, 256, 0, stream>>>(bsum, boff, nb);
    scanfin_k<<<nb, 256, 0, stream>>>(cnt, boff, start, fill, N, E);
    csr_fill<<<(E + 255) / 256, 256, 0, stream>>>(esrc, edst, dis, start, fill, csrs, csrn, E);

    // 3. retrieval FIRST: fp8 approx -> filter -> exact fp32 rescore -> top-K
    mfma_bert8<<<(N + 127) / 128, 256, 0, stream>>>(Qb8, bufX8, sparse, sweight, approxScore, B, N);
    int chunk = (N + FCH - 1) / FCH;
    dim3 fgrid(FCH, B);
    filter_topc<<<fgrid, 256, (size_t)chunk * 4, stream>>>(approxScore, candIdx, N, chunk);
    dim3 rgrid(NCAND / 64, B);
    rescore_kernel<<<rgrid, 256, 0, stream>>>(q_emb, x_emb, sparse, sweight, candIdx, resVal, N);
    select_topk<<<B, 256, 0, stream>>>(resVal, candIdx, q_idx, candBuf, outIdx, K);

    // 4. mark candidate rows + in-neighbors; compact to RL
    mark_rows<<<(B * K + 3) / 4, 256, 0, stream>>>(candBuf, start, csrs, flag, B * K);
    compact_rows<<<nb, 256, 0, stream>>>(flag, RL, rcp, N);

    // 5. GCN layer 1: full GEMM (h1 needed at ~all rows), agg only at RL rows
    const int nTilesM = (N + 127) / 128;
    const int nTilesN = D / 128;             // 6
    const int gemmWG  = nTilesM * nTilesN;
    gemm_fp8<<<gemmWG, 256, 0, stream>>>(bufX8, W1t8, bufH8, N, nTilesN);
    agg_fp8<true, true><<<(N + 3) / 4, 256, 0, stream>>>(bufH8, bufG8, start, csrs, csrn, dis, b1, RL, rcp, 1, N);

    // 6. GCN layer 2, sparse: h2 only at RL rows; agg only at candidate rows
    gemm_fp8_list<<<gemmWG, 256, 0, stream>>>(bufG8, W2t8, bufH8, RL, rcp, nTilesN);
    agg_fp8<false, true><<<(B * K + 3) / 4, 256, 0, stream>>>(bufH8, bufG, start, csrs, csrn, dis, b2, candBuf, nullptr, 0, B * K);

    // 7. final scoring head
    final_kernel<<<(B * K + 3) / 4, 256, 0, stream>>>(bufG, q_emb, candBuf, scoreW, scoreB, outScore, B, K);
}